// Round 7
// baseline (421.463 us; speedup 1.0000x reference)
//
#include <hip/hip_runtime.h>
#include <hip/hip_bf16.h>
#include <hip/hip_fp16.h>

#define NB 8192
#define D_IN 3200
#define D_H 128
#define NE 5

typedef _Float16 f16x8 __attribute__((ext_vector_type(8)));
typedef _Float16 f16x4 __attribute__((ext_vector_type(4)));
typedef _Float16 f16x2 __attribute__((ext_vector_type(2)));
typedef float f32x4 __attribute__((ext_vector_type(4)));

// async global->LDS, 16B per lane; lds base wave-uniform, lanes land at base+lane*16
__device__ __forceinline__ void gload16(const _Float16* g, _Float16* l) {
    __builtin_amdgcn_global_load_lds(
        (const __attribute__((address_space(1))) void*)g,
        (__attribute__((address_space(3))) void*)l, 16, 0, 0);
}

// ---------------- kernel 0: e1_w [5][3200][128] f32 -> f16 transposed [5][128][3200]
__global__ __launch_bounds__(256) void k_wconv(const float* __restrict__ e1w,
                                               _Float16* __restrict__ wT) {
    __shared__ float tile[64][65];
    int e = blockIdx.x;
    int k0 = blockIdx.y * 64;
    int n0 = blockIdx.z * 64;
    const float* src = e1w + (size_t)e * D_IN * D_H;
    _Float16* dst = wT + (size_t)e * D_H * D_IN;
    int t = threadIdx.x;
    for (int i = 0; i < 16; ++i) {
        int idx = t + i * 256;
        int kr = idx >> 6, nc = idx & 63;
        tile[kr][nc] = src[(size_t)(k0 + kr) * D_H + n0 + nc];
    }
    __syncthreads();
    for (int i = 0; i < 16; ++i) {
        int idx = t + i * 256;
        int nr = idx >> 6, kc = idx & 63;
        dst[(size_t)(n0 + nr) * D_IN + k0 + kc] = (_Float16)tile[kc][nr];
    }
}

// ---------------- kernel 0b: e2_w [5][128][128] f32 -> f16 transposed (n,k)
__global__ __launch_bounds__(256) void k_wprep2(const float* __restrict__ e2w,
                                                _Float16* __restrict__ e2T) {
    __shared__ float tile[64][65];
    int e = blockIdx.x;
    int k0 = blockIdx.y * 64;
    int n0 = blockIdx.z * 64;
    const float* src = e2w + (size_t)e * D_H * D_H;
    _Float16* dst = e2T + (size_t)e * D_H * D_H;
    int t = threadIdx.x;
    for (int i = 0; i < 16; ++i) {
        int idx = t + i * 256;
        int kr = idx >> 6, nc = idx & 63;
        tile[kr][nc] = src[(size_t)(k0 + kr) * D_H + n0 + nc];
    }
    __syncthreads();
    for (int i = 0; i < 16; ++i) {
        int idx = t + i * 256;
        int nr = idx >> 6, kc = idx & 63;
        dst[(size_t)(n0 + nr) * D_H + k0 + kc] = (_Float16)tile[kc][nr];
    }
}

// ---------------- kernel 0c: gw [3200][5] -> gwC [5][100(o)][32(co)]
__global__ __launch_bounds__(256) void k_wgate(const float* __restrict__ gw,
                                               float* __restrict__ gwC) {
    int i = blockIdx.x * 256 + threadIdx.x;
    if (i < 16000) {
        int e = i / 3200, rem = i - e * 3200;
        int o = rem >> 5, co = rem & 31;
        gwC[i] = gw[(co * 100 + o) * 5 + e];
    }
}

// ---------------- kernel 1: conv1 via im2col MFMA (4 chunks) -> pool -> conv2 MFMA -> h16+gate
// Tap layout k' = u*6+v (rows even-aligned for paired writes; gaps zeroed in A and B).
// hi/lo f16 splits everywhere on the gate-feeding path (top-3 select is discontinuous).
#define PCL_S 24
#define IM2S 40    // im2col row stride (halves): 80B, 16B-aligned f16x8 reads, spread banks
#define C1S 17     // c1out row stride (floats): breaks 4-way epilogue-write conflicts
#define B2S 168    // b2 row stride (halves): 336B, 16B-aligned, spread banks
__global__ __launch_bounds__(256, 3) void k_feat(
    const float* __restrict__ x, const float* __restrict__ c1w, const float* __restrict__ c1b,
    const float* __restrict__ c2w, const float* __restrict__ c2b,
    const float* __restrict__ gwC, const float* __restrict__ gb,
    _Float16* __restrict__ h16, float* __restrict__ wfull)
{
    __shared__ union {
        struct {                                   // conv1 phase
            __align__(16) _Float16 im2h[144 * IM2S];   // 11520 B
            __align__(16) _Float16 im2l[144 * IM2S];   // 11520 B
            __align__(16) float c1out[144 * C1S];      // 9792 B
        } s1;
        struct {                                   // conv2 phase
            __align__(16) _Float16 b2h[32 * B2S];      // 10752 B
            __align__(16) _Float16 b2l[32 * B2S];      // 10752 B
        } s2;
    } u;
    __shared__ __align__(16) _Float16 w1h[16 * 32];     // [ch][k'] conv1 weights hi
    __shared__ __align__(16) _Float16 w1l[16 * 32];     // lo
    __shared__ __align__(16) _Float16 pclh[144 * PCL_S];
    __shared__ __align__(16) _Float16 pcll[144 * PCL_S];
    __shared__ float red[4][8];
    int b = blockIdx.x;
    int t = threadIdx.x;
    int lane = t & 63, wv = t >> 6;
    int quad = lane >> 4, l16 = lane & 15;
    const float* xb = x + (size_t)b * 784;

    // ---- stage conv1 weights [ch][k'=u*6+v] hi/lo, zeros elsewhere
    for (int i = t; i < 512; i += 256) {
        int ch = i >> 5, k = i & 31;
        int uu = k / 6, vv = k - uu * 6;
        float val = (uu < 5 && vv < 5) ? c1w[ch * 25 + uu * 5 + vv] : 0.f;
        _Float16 vh = (_Float16)val;
        w1h[i] = vh;
        w1l[i] = (_Float16)(val - (float)vh);
    }
    // prefill im2 pad slots 30,31 (never written by build; must be finite: NaN*0=NaN in MFMA)
    for (int j = t; j < 144; j += 256) {
        *(f16x2*)&u.s1.im2h[j * IM2S + 30] = (f16x2){(_Float16)0.f, (_Float16)0.f};
        *(f16x2*)&u.s1.im2l[j * IM2S + 30] = (f16x2){(_Float16)0.f, (_Float16)0.f};
    }
    __syncthreads();

    f16x8 b1h = *(const f16x8*)&w1h[l16 * 32 + quad * 8];
    f16x8 b1l = *(const f16x8*)&w1l[l16 * 32 + quad * 8];
    float c1b_l = c1b[l16];

    // ---- 4 chunks of 6 image rows (144 conv1 outputs each)
    for (int c = 0; c < 4; ++c) {
        // build im2col: 288 jobs = 144 pos x 2 halves (rows {0,1} / {2,3,4})
        for (int j = t; j < 288; j += 256) {
            int pos = j >> 1, half = j & 1;
            int lr = pos / 24, lc = pos - lr * 24;
            int gr = c * 6 + lr;
            int u0 = half ? 2 : 0, u1 = half ? 5 : 2;
            for (int uu = u0; uu < u1; ++uu) {
                const float* xr = xb + (gr + uu) * 28 + lc;
                float f0 = xr[0], f1 = xr[1], f2 = xr[2], f3 = xr[3], f4 = xr[4];
                _Float16 a0 = (_Float16)f0, a1 = (_Float16)f1, a2 = (_Float16)f2,
                         a3 = (_Float16)f3, a4 = (_Float16)f4;
                int base = pos * IM2S + uu * 6;
                *(f16x2*)&u.s1.im2h[base]     = (f16x2){a0, a1};
                *(f16x2*)&u.s1.im2h[base + 2] = (f16x2){a2, a3};
                *(f16x2*)&u.s1.im2h[base + 4] = (f16x2){a4, (_Float16)0.f};
                _Float16 l0 = (_Float16)(f0 - (float)a0), l1 = (_Float16)(f1 - (float)a1),
                         l2 = (_Float16)(f2 - (float)a2), l3 = (_Float16)(f3 - (float)a3),
                         l4 = (_Float16)(f4 - (float)a4);
                *(f16x2*)&u.s1.im2l[base]     = (f16x2){l0, l1};
                *(f16x2*)&u.s1.im2l[base + 2] = (f16x2){l2, l3};
                *(f16x2*)&u.s1.im2l[base + 4] = (f16x2){l4, (_Float16)0.f};
            }
        }
        __syncthreads();
        // conv1 MFMA: 9 m-tiles, 3 hi/lo passes each; epilogue relu -> c1out f32
        for (int mt = wv; mt < 9; mt += 4) {
            f16x8 ah = *(const f16x8*)&u.s1.im2h[(mt * 16 + l16) * IM2S + quad * 8];
            f16x8 al = *(const f16x8*)&u.s1.im2l[(mt * 16 + l16) * IM2S + quad * 8];
            f32x4 a1 = (f32x4){0.f, 0.f, 0.f, 0.f};
            a1 = __builtin_amdgcn_mfma_f32_16x16x32_f16(ah, b1h, a1, 0, 0, 0);
            a1 = __builtin_amdgcn_mfma_f32_16x16x32_f16(ah, b1l, a1, 0, 0, 0);
            a1 = __builtin_amdgcn_mfma_f32_16x16x32_f16(al, b1h, a1, 0, 0, 0);
            int p0 = mt * 16 + quad * 4;     // C/D: row=quad*4+r (pos), col=l16 (ch)
            #pragma unroll
            for (int r = 0; r < 4; ++r)
                u.s1.c1out[(p0 + r) * C1S + l16] = fmaxf(a1[r] + c1b_l, 0.f);
        }
        __syncthreads();
        // 2x2 maxpool -> pcl (channel-last, hi/lo)
        for (int j = t; j < 576; j += 256) {
            int ch = j & 15, rest = j >> 4;      // rest 0..35
            int pc = rest % 12, pr = rest / 12;  // pr 0..2
            int p0 = pr * 48 + pc * 2;           // local pos (2pr)*24 + 2pc
            float v = fmaxf(fmaxf(u.s1.c1out[p0 * C1S + ch], u.s1.c1out[(p0 + 1) * C1S + ch]),
                            fmaxf(u.s1.c1out[(p0 + 24) * C1S + ch], u.s1.c1out[(p0 + 25) * C1S + ch]));
            int gp = (3 * c + pr) * 12 + pc;
            _Float16 vh = (_Float16)v;
            pclh[gp * PCL_S + ch] = vh;
            pcll[gp * PCL_S + ch] = (_Float16)(v - (float)vh);
        }
        __syncthreads();   // pool done before next chunk overwrites im2/c1out
    }

    // ---- stage conv2 weights hi/lo into union (im2/c1out dead)
    for (int i = t; i < 5120; i += 256) {
        int co = i / 160, k = i - co * 160;
        int s = k >> 4, ci = k & 15;
        float v = (s == 9) ? 0.f : c2w[(co * 16 + ci) * 9 + s];
        _Float16 vh = (_Float16)v;
        u.s2.b2h[co * B2S + k] = vh;
        u.s2.b2l[co * B2S + k] = (_Float16)(v - (float)vh);
    }
    __syncthreads();

    // ---- conv2 MFMA: wave fixed nt (B frags in regs), mt strided
    float part[5] = {0, 0, 0, 0, 0};
    int quadh = quad >> 1, quadl = quad & 1;
    const int offA[5] = {0, 2, 13, 24, 26};   // shifts s=0,2,4,6,8
    const int offB[5] = {1, 12, 14, 25, 0};   // shifts s=1,3,5,7,9 (9 dummy, B=0)
    {
        int nt = wv & 1;
        int co = nt * 16 + l16;
        f16x8 bh[5], bl[5];
        #pragma unroll
        for (int kc = 0; kc < 5; ++kc) {
            bh[kc] = *(const f16x8*)&u.s2.b2h[co * B2S + kc * 32 + quad * 8];
            bl[kc] = *(const f16x8*)&u.s2.b2l[co * B2S + kc * 32 + quad * 8];
        }
        float bco = c2b[co];
        for (int mt = wv >> 1; mt < 7; mt += 2) {
            int o_a = mt * 16 + l16;
            int o_cl = o_a < 100 ? o_a : 99;
            int pb = (o_cl / 10) * 12 + (o_cl % 10);
            f32x4 acc = (f32x4){0.f, 0.f, 0.f, 0.f};
            #pragma unroll
            for (int kc = 0; kc < 5; ++kc) {
                int off = quadh ? offB[kc] : offA[kc];
                f16x8 ah = *(const f16x8*)&pclh[(pb + off) * PCL_S + quadl * 8];
                f16x8 al = *(const f16x8*)&pcll[(pb + off) * PCL_S + quadl * 8];
                acc = __builtin_amdgcn_mfma_f32_16x16x32_f16(ah, bh[kc], acc, 0, 0, 0);
                acc = __builtin_amdgcn_mfma_f32_16x16x32_f16(ah, bl[kc], acc, 0, 0, 0);
                acc = __builtin_amdgcn_mfma_f32_16x16x32_f16(al, bh[kc], acc, 0, 0, 0);
            }
            if (mt < 6 || quad == 0) {
                int o0 = mt * 16 + quad * 4;
                f16x4 st;
                #pragma unroll
                for (int r = 0; r < 4; ++r) {
                    float hv = fmaxf(acc[r] + bco, 0.f);
                    st[r] = (_Float16)hv;
                    #pragma unroll
                    for (int e = 0; e < 5; ++e)
                        part[e] += hv * gwC[e * 3200 + (o0 + r) * 32 + co];
                }
                *(f16x4*)&h16[(size_t)b * D_IN + co * 100 + o0] = st;
            }
        }
    }

    // ---- gate reduce: softmax, top-3 renormalized
    #pragma unroll
    for (int e = 0; e < 5; ++e) {
        float v = part[e];
        for (int off = 32; off > 0; off >>= 1) v += __shfl_down(v, off, 64);
        if (lane == 0) red[wv][e] = v;
    }
    __syncthreads();
    if (t == 0) {
        float lg[5], p[5];
        float mx = -1e30f;
        for (int e = 0; e < 5; ++e) {
            lg[e] = red[0][e] + red[1][e] + red[2][e] + red[3][e] + gb[e];
            mx = fmaxf(mx, lg[e]);
        }
        float sum = 0.f;
        for (int e = 0; e < 5; ++e) { p[e] = expf(lg[e] - mx); sum += p[e]; }
        for (int e = 0; e < 5; ++e) p[e] /= sum;
        bool used[5] = {false, false, false, false, false};
        float out5[5] = {0, 0, 0, 0, 0};
        int ti[3]; float tv[3]; float tsum = 0.f;
        for (int jj = 0; jj < 3; ++jj) {
            int best = 0; float bv = -1.f;
            for (int e = 0; e < 5; ++e)
                if (!used[e] && p[e] > bv) { bv = p[e]; best = e; }
            used[best] = true; ti[jj] = best; tv[jj] = bv; tsum += bv;
        }
        for (int jj = 0; jj < 3; ++jj) out5[ti[jj]] = tv[jj] / tsum;
        for (int e = 0; e < 5; ++e) wfull[b * 5 + e] = out5[e];
    }
}

// ---------------- kernel 2: fused experts, 64-row M-tile, global_load_lds staging.
// Grid flat 640; XCD-swizzle: 5 experts of each m-tile co-located per XCD for L2 A-reuse.
#define H1S 136
union SLds {
    struct { _Float16 As[64 * 32]; _Float16 Bs[128 * 32]; } p1;  // e1 staging (unpadded)
    _Float16 e2ws[128 * H1S];                                    // e2 weights (padded)
};

__global__ __launch_bounds__(256, 3) void k_e1e2(
    const _Float16* __restrict__ h16, const _Float16* __restrict__ wT,
    const _Float16* __restrict__ e2T,
    const float* __restrict__ e1b, const float* __restrict__ e2b,
    const float* __restrict__ wfull, float* __restrict__ moe)
{
    __shared__ SLds u;
    __shared__ __align__(16) _Float16 h1s[64 * H1S];
    __shared__ float wfl[64];
    int bid = blockIdx.x;
    int xcd = bid & 7, slot = bid >> 3;     // 80 slots/XCD
    int mtile = xcd * 16 + slot / 5;
    int e = slot % 5;
    int m0 = mtile * 64;
    int t = threadIdx.x;
    int lane = t & 63, wv = t >> 6;
    int waveM = wv >> 1, waveN = wv & 1;
    int quad = lane >> 4, l16 = lane & 15;
    if (t < 64) wfl[t] = wfull[(size_t)(m0 + t) * 5 + e];

    const _Float16* abase = h16 + (size_t)m0 * D_IN;
    const _Float16* bbase = wT + (size_t)e * (D_H * D_IN);
    int srow = t >> 2;
    int scol = (t & 3) * 8;
    f32x4 acc[2][4];
    #pragma unroll
    for (int i = 0; i < 2; ++i)
        #pragma unroll
        for (int j = 0; j < 4; ++j) acc[i][j] = (f32x4){0.f, 0.f, 0.f, 0.f};

    for (int k0 = 0; k0 < D_IN; k0 += 32) {
        gload16(abase + (size_t)srow * D_IN + k0 + scol,        u.p1.As + wv * 512);
        gload16(bbase + (size_t)srow * D_IN + k0 + scol,        u.p1.Bs + wv * 512);
        gload16(bbase + (size_t)(64 + srow) * D_IN + k0 + scol, u.p1.Bs + 2048 + wv * 512);
        __syncthreads();
        f16x8 af[2], bf[4];
        #pragma unroll
        for (int ms = 0; ms < 2; ++ms)
            af[ms] = *(const f16x8*)&u.p1.As[(waveM * 32 + ms * 16 + l16) * 32 + quad * 8];
        #pragma unroll
        for (int ns = 0; ns < 4; ++ns)
            bf[ns] = *(const f16x8*)&u.p1.Bs[(waveN * 64 + ns * 16 + l16) * 32 + quad * 8];
        #pragma unroll
        for (int ms = 0; ms < 2; ++ms)
            #pragma unroll
            for (int ns = 0; ns < 4; ++ns)
                acc[ms][ns] = __builtin_amdgcn_mfma_f32_16x16x32_f16(af[ms], bf[ns], acc[ms][ns], 0, 0, 0);
        __syncthreads();
    }

    #pragma unroll
    for (int ms = 0; ms < 2; ++ms) {
        int rbase = waveM * 32 + ms * 16 + quad * 4;
        #pragma unroll
        for (int ns = 0; ns < 4; ++ns) {
            int n = waveN * 64 + ns * 16 + l16;
            float bias = e1b[e * D_H + n];
            #pragma unroll
            for (int r = 0; r < 4; ++r)
                h1s[(rbase + r) * H1S + n] = (_Float16)tanhf(acc[ms][ns][r] + bias);
        }
    }
    __syncthreads();

    {
        int rr = t >> 1, cc = (t & 1) * 64;
        const _Float16* src = e2T + (size_t)e * (D_H * D_H) + (size_t)rr * D_H + cc;
        #pragma unroll
        for (int i = 0; i < 8; ++i)
            *(uint4*)&u.e2ws[rr * H1S + cc + i * 8] = *(const uint4*)(src + i * 8);
    }
    __syncthreads();

    f32x4 acc2[2][4];
    #pragma unroll
    for (int i = 0; i < 2; ++i)
        #pragma unroll
        for (int j = 0; j < 4; ++j) acc2[i][j] = (f32x4){0.f, 0.f, 0.f, 0.f};
    #pragma unroll
    for (int kc = 0; kc < 4; ++kc) {
        f16x8 a2[2], b2[4];
        #pragma unroll
        for (int ms = 0; ms < 2; ++ms)
            a2[ms] = *(const f16x8*)&h1s[(waveM * 32 + ms * 16 + l16) * H1S + kc * 32 + quad * 8];
        #pragma unroll
        for (int ns = 0; ns < 4; ++ns)
            b2[ns] = *(const f16x8*)&u.e2ws[(waveN * 64 + ns * 16 + l16) * H1S + kc * 32 + quad * 8];
        #pragma unroll
        for (int ms = 0; ms < 2; ++ms)
            #pragma unroll
            for (int ns = 0; ns < 4; ++ns)
                acc2[ms][ns] = __builtin_amdgcn_mfma_f32_16x16x32_f16(a2[ms], b2[ns], acc2[ms][ns], 0, 0, 0);
    }

    #pragma unroll
    for (int ms = 0; ms < 2; ++ms) {
        int rbase = waveM * 32 + ms * 16 + quad * 4;
        #pragma unroll
        for (int ns = 0; ns < 4; ++ns) {
            int n = waveN * 64 + ns * 16 + l16;
            float bias = e2b[e * D_H + n];
            #pragma unroll
            for (int r = 0; r < 4; ++r) {
                int row = rbase + r;
                float w = wfl[row];
                if (w != 0.f) {
                    float h2 = tanhf(acc2[ms][ns][r] + bias);
                    unsafeAtomicAdd(&moe[(size_t)(m0 + row) * D_H + n], w * h2);
                }
            }
        }
    }
}

// ---------------- kernel 3: head: logits = moe @ smw + smb, softmax -> out
__global__ __launch_bounds__(256) void k_head(
    const float* __restrict__ moe, const float* __restrict__ smw,
    const float* __restrict__ smb, float* __restrict__ out)
{
    __shared__ float moesT[128 * 66];
    __shared__ float smws[1280];
    __shared__ float smbs[16];
    __shared__ float lg[64 * 12];
    int b0 = blockIdx.x * 64;
    int t = threadIdx.x;
    for (int i = t; i < 1280; i += 256) smws[i] = smw[i];
    if (t < 10) smbs[t] = smb[t];
    {
        int row = t >> 2, cb = (t & 3) * 32;
        #pragma unroll
        for (int i = 0; i < 8; ++i) {
            float4 v = *(const float4*)&moe[(size_t)(b0 + row) * D_H + cb + i * 4];
            moesT[(cb + i * 4 + 0) * 66 + row] = v.x;
            moesT[(cb + i * 4 + 1) * 66 + row] = v.y;
            moesT[(cb + i * 4 + 2) * 66 + row] = v.z;
            moesT[(cb + i * 4 + 3) * 66 + row] = v.w;
        }
    }
    __syncthreads();
    {
        int row = t & 63, grp = t >> 6;
        int c0 = grp, c1 = grp + 4, c2 = grp + 8;
        float s0 = 0.f, s1 = 0.f, s2 = 0.f;
        for (int k = 0; k < 128; ++k) {
            float m = moesT[k * 66 + row];
            s0 += m * smws[k * 10 + c0];
            s1 += m * smws[k * 10 + c1];
            if (c2 < 10) s2 += m * smws[k * 10 + c2];
        }
        lg[row * 12 + c0] = s0 + smbs[c0];
        lg[row * 12 + c1] = s1 + smbs[c1];
        if (c2 < 10) lg[row * 12 + c2] = s2 + smbs[c2];
    }
    __syncthreads();
    if (t < 64) {
        float mx = -1e30f;
        for (int c = 0; c < 10; ++c) mx = fmaxf(mx, lg[t * 12 + c]);
        float s = 0.f, ex[10];
        for (int c = 0; c < 10; ++c) { ex[c] = expf(lg[t * 12 + c] - mx); s += ex[c]; }
        float inv = 1.f / s;
        for (int c = 0; c < 10; ++c) out[(size_t)(b0 + t) * 10 + c] = ex[c] * inv;
    }
}

extern "C" void kernel_launch(void* const* d_in, const int* in_sizes, int n_in,
                              void* d_out, int out_size, void* d_ws, size_t ws_size,
                              hipStream_t stream)
{
    const float* x   = (const float*)d_in[0];
    const float* c1w = (const float*)d_in[1];
    const float* c1b = (const float*)d_in[2];
    const float* c2w = (const float*)d_in[3];
    const float* c2b = (const float*)d_in[4];
    const float* gw  = (const float*)d_in[5];
    const float* gb  = (const float*)d_in[6];
    const float* e1w = (const float*)d_in[7];
    const float* e1b = (const float*)d_in[8];
    const float* e2w = (const float*)d_in[9];
    const float* e2b = (const float*)d_in[10];
    const float* smw = (const float*)d_in[11];
    const float* smb = (const float*)d_in[12];
    float* out = (float*)d_out;

    char* ws = (char*)d_ws;
    size_t off = 0;
    auto alloc = [&](size_t bytes) {
        void* p = ws + off;
        off += (bytes + 255) & ~(size_t)255;
        return p;
    };
    _Float16* h16 = (_Float16*)alloc((size_t)NB * D_IN * 2);          // 52.4 MB
    _Float16* wT  = (_Float16*)alloc((size_t)NE * D_H * D_IN * 2);    // 4.1 MB
    _Float16* e2T = (_Float16*)alloc((size_t)NE * D_H * D_H * 2);     // 0.16 MB
    float* wfull  = (float*)alloc((size_t)NB * NE * 4);               // 0.16 MB
    float* moe    = (float*)alloc((size_t)NB * D_H * 4);              // 4.2 MB
    float* gwC    = (float*)alloc((size_t)NE * D_IN * 4);             // 64 KB

    hipMemsetAsync(moe, 0, (size_t)NB * D_H * 4, stream);
    k_wconv<<<dim3(NE, D_IN / 64, D_H / 64), 256, 0, stream>>>(e1w, wT);
    k_wprep2<<<dim3(NE, 2, 2), 256, 0, stream>>>(e2w, e2T);
    k_wgate<<<dim3(63), 256, 0, stream>>>(gw, gwC);
    k_feat<<<dim3(NB), 256, 0, stream>>>(x, c1w, c1b, c2w, c2b, gwC, gb, h16, wfull);
    k_e1e2<<<dim3(NB / 64 * NE), 256, 0, stream>>>(h16, wT, e2T, e1b, e2b, wfull, moe);
    k_head<<<dim3(NB / 64), 256, 0, stream>>>(moe, smw, smb, out);
}

// Round 8
// 343.289 us; speedup vs baseline: 1.2277x; 1.2277x over previous
//
#include <hip/hip_runtime.h>
#include <hip/hip_bf16.h>
#include <hip/hip_fp16.h>

#define NB 8192
#define D_IN 3200
#define D_H 128
#define NE 5

typedef _Float16 f16x8 __attribute__((ext_vector_type(8)));
typedef _Float16 f16x4 __attribute__((ext_vector_type(4)));
typedef float f32x4 __attribute__((ext_vector_type(4)));

// async global->LDS, 16B per lane; global addr may be per-lane, LDS base wave-uniform
__device__ __forceinline__ void gload16(const _Float16* g, _Float16* l) {
    __builtin_amdgcn_global_load_lds(
        (const __attribute__((address_space(1))) void*)g,
        (__attribute__((address_space(3))) void*)l, 16, 0, 0);
}

// ---------------- kernel 0: e1_w [5][3200][128] f32 -> f16 transposed [5][128][3200]
__global__ __launch_bounds__(256) void k_wconv(const float* __restrict__ e1w,
                                               _Float16* __restrict__ wT) {
    __shared__ float tile[64][65];
    int e = blockIdx.x;
    int k0 = blockIdx.y * 64;
    int n0 = blockIdx.z * 64;
    const float* src = e1w + (size_t)e * D_IN * D_H;
    _Float16* dst = wT + (size_t)e * D_H * D_IN;
    int t = threadIdx.x;
    for (int i = 0; i < 16; ++i) {
        int idx = t + i * 256;
        int kr = idx >> 6, nc = idx & 63;
        tile[kr][nc] = src[(size_t)(k0 + kr) * D_H + n0 + nc];
    }
    __syncthreads();
    for (int i = 0; i < 16; ++i) {
        int idx = t + i * 256;
        int nr = idx >> 6, kc = idx & 63;
        dst[(size_t)(n0 + nr) * D_IN + k0 + kc] = (_Float16)tile[kc][nr];
    }
}

// ---------------- kernel 0b: e2_w [5][128][128] f32 -> f16 transposed (n,k)
__global__ __launch_bounds__(256) void k_wprep2(const float* __restrict__ e2w,
                                                _Float16* __restrict__ e2T) {
    __shared__ float tile[64][65];
    int e = blockIdx.x;
    int k0 = blockIdx.y * 64;
    int n0 = blockIdx.z * 64;
    const float* src = e2w + (size_t)e * D_H * D_H;
    _Float16* dst = e2T + (size_t)e * D_H * D_H;
    int t = threadIdx.x;
    for (int i = 0; i < 16; ++i) {
        int idx = t + i * 256;
        int kr = idx >> 6, nc = idx & 63;
        tile[kr][nc] = src[(size_t)(k0 + kr) * D_H + n0 + nc];
    }
    __syncthreads();
    for (int i = 0; i < 16; ++i) {
        int idx = t + i * 256;
        int nr = idx >> 6, kc = idx & 63;
        dst[(size_t)(n0 + nr) * D_H + k0 + kc] = (_Float16)tile[kc][nr];
    }
}

// ---------------- kernel 0c: gw [3200][5] -> gwC [5][100(o)][32(co)]
__global__ __launch_bounds__(256) void k_wgate(const float* __restrict__ gw,
                                               float* __restrict__ gwC) {
    int i = blockIdx.x * 256 + threadIdx.x;
    if (i < 16000) {
        int e = i / 3200, rem = i - e * 3200;
        int o = rem >> 5, co = rem & 31;
        gwC[i] = gw[(co * 100 + o) * 5 + e];
    }
}

// ---------------- kernel 1: conv1+pool (scalar, LDS window) -> conv2 shifted-GEMM MFMA
// Best-measured variant (R5 bench: ~167us). conv1 surgery abandoned after 3 regressions.
#define PCL_S 24
__global__ __launch_bounds__(256, 3) void k_feat(
    const float* __restrict__ x, const float* __restrict__ c1w, const float* __restrict__ c1b,
    const float* __restrict__ c2w, const float* __restrict__ c2b,
    const float* __restrict__ gwC, const float* __restrict__ gb,
    _Float16* __restrict__ h16, float* __restrict__ wfull)
{
    __shared__ __align__(16) float xs[784];
    __shared__ __align__(16) float c1wsP[16 * 28];
    __shared__ __align__(16) _Float16 b2h[32 * 160];
    __shared__ __align__(16) _Float16 b2l[32 * 160];
    __shared__ __align__(16) _Float16 pclh[144 * PCL_S];
    __shared__ __align__(16) _Float16 pcll[144 * PCL_S];
    __shared__ float red[4][8];
    int b = blockIdx.x;
    int t = threadIdx.x;

    for (int i = t; i < 784; i += 256) xs[i] = x[(size_t)b * 784 + i];
    for (int i = t; i < 400; i += 256) {
        int c = i / 25, q = i - c * 25;
        c1wsP[c * 28 + q] = c1w[i];
    }
    for (int i = t; i < 5120; i += 256) {
        int co = i / 160, k = i - co * 160;
        int s = k >> 4, ci = k & 15;
        float v = (s == 9) ? 0.f : c2w[(co * 16 + ci) * 9 + s];
        _Float16 vh = (_Float16)v;
        b2h[i] = vh;
        b2l[i] = (_Float16)(v - (float)vh);
    }
    __syncthreads();

    // ---- conv1 + 2x2 maxpool -> pcl channel-last (hi/lo f16)
    {
        int c = t >> 4;
        int tile = t & 15;
        int tr = tile >> 2, tc = tile & 3;
        float w1r[25];
        #pragma unroll
        for (int q = 0; q < 6; ++q) {
            float4 v4 = *(const float4*)&c1wsP[c * 28 + q * 4];
            w1r[q * 4 + 0] = v4.x; w1r[q * 4 + 1] = v4.y;
            w1r[q * 4 + 2] = v4.z; w1r[q * 4 + 3] = v4.w;
        }
        w1r[24] = c1wsP[c * 28 + 24];
        float bias1 = c1b[c];
        float win[5][10];
        float pacc[3][3];
        #pragma unroll
        for (int i = 0; i < 3; ++i)
            #pragma unroll
            for (int j = 0; j < 3; ++j) pacc[i][j] = 0.f;
        int r0 = 6 * tr, col0 = 6 * tc;
        #pragma unroll
        for (int cr = 0; cr < 6; ++cr) {
            if (cr == 0) {
                #pragma unroll
                for (int rr = 0; rr < 5; ++rr)
                    #pragma unroll
                    for (int m = 0; m < 5; ++m) {
                        float2 v = *(const float2*)&xs[(r0 + rr) * 28 + col0 + 2 * m];
                        win[rr][2 * m] = v.x; win[rr][2 * m + 1] = v.y;
                    }
            } else {
                int dstr = (cr + 4) % 5;
                #pragma unroll
                for (int m = 0; m < 5; ++m) {
                    float2 v = *(const float2*)&xs[(r0 + cr + 4) * 28 + col0 + 2 * m];
                    win[dstr][2 * m] = v.x; win[dstr][2 * m + 1] = v.y;
                }
            }
            #pragma unroll
            for (int oc = 0; oc < 6; ++oc) {
                float s = bias1;
                #pragma unroll
                for (int u = 0; u < 5; ++u)
                    #pragma unroll
                    for (int v = 0; v < 5; ++v)
                        s += win[(cr + u) % 5][oc + v] * w1r[u * 5 + v];
                s = fmaxf(s, 0.f);
                pacc[cr >> 1][oc >> 1] = fmaxf(pacc[cr >> 1][oc >> 1], s);
            }
        }
        #pragma unroll
        for (int i = 0; i < 3; ++i)
            #pragma unroll
            for (int j = 0; j < 3; ++j) {
                int pos = (3 * tr + i) * 12 + (3 * tc + j);
                float v = pacc[i][j];
                _Float16 vh = (_Float16)v;
                pclh[pos * PCL_S + c] = vh;
                pcll[pos * PCL_S + c] = (_Float16)(v - (float)vh);
            }
    }
    __syncthreads();

    // ---- conv2 MFMA: wave fixed nt (B frags in regs), mt strided
    float part[5] = {0, 0, 0, 0, 0};
    int lane = t & 63, wv = t >> 6;
    int quad = lane >> 4, l16 = lane & 15;
    int quadh = quad >> 1, quadl = quad & 1;
    const int offA[5] = {0, 2, 13, 24, 26};   // shifts s=0,2,4,6,8
    const int offB[5] = {1, 12, 14, 25, 0};   // shifts s=1,3,5,7,9 (9 dummy, B=0)
    {
        int nt = wv & 1;
        int co = nt * 16 + l16;
        f16x8 bh[5], bl[5];
        #pragma unroll
        for (int kc = 0; kc < 5; ++kc) {
            bh[kc] = *(const f16x8*)&b2h[co * 160 + kc * 32 + quad * 8];
            bl[kc] = *(const f16x8*)&b2l[co * 160 + kc * 32 + quad * 8];
        }
        float bco = c2b[co];
        for (int mt = wv >> 1; mt < 7; mt += 2) {
            int o_a = mt * 16 + l16;
            int o_cl = o_a < 100 ? o_a : 99;
            int pb = (o_cl / 10) * 12 + (o_cl % 10);
            f32x4 acc = (f32x4){0.f, 0.f, 0.f, 0.f};
            #pragma unroll
            for (int kc = 0; kc < 5; ++kc) {
                int off = quadh ? offB[kc] : offA[kc];
                f16x8 ah = *(const f16x8*)&pclh[(pb + off) * PCL_S + quadl * 8];
                f16x8 al = *(const f16x8*)&pcll[(pb + off) * PCL_S + quadl * 8];
                acc = __builtin_amdgcn_mfma_f32_16x16x32_f16(ah, bh[kc], acc, 0, 0, 0);
                acc = __builtin_amdgcn_mfma_f32_16x16x32_f16(ah, bl[kc], acc, 0, 0, 0);
                acc = __builtin_amdgcn_mfma_f32_16x16x32_f16(al, bh[kc], acc, 0, 0, 0);
            }
            if (mt < 6 || quad == 0) {
                int o0 = mt * 16 + quad * 4;
                f16x4 st;
                #pragma unroll
                for (int r = 0; r < 4; ++r) {
                    float hv = fmaxf(acc[r] + bco, 0.f);
                    st[r] = (_Float16)hv;
                    #pragma unroll
                    for (int e = 0; e < 5; ++e)
                        part[e] += hv * gwC[e * 3200 + (o0 + r) * 32 + co];
                }
                *(f16x4*)&h16[(size_t)b * D_IN + co * 100 + o0] = st;
            }
        }
    }

    // ---- gate reduce: softmax, top-3 renormalized
    #pragma unroll
    for (int e = 0; e < 5; ++e) {
        float v = part[e];
        for (int off = 32; off > 0; off >>= 1) v += __shfl_down(v, off, 64);
        if (lane == 0) red[wv][e] = v;
    }
    __syncthreads();
    if (t == 0) {
        float lg[5], p[5];
        float mx = -1e30f;
        for (int e = 0; e < 5; ++e) {
            lg[e] = red[0][e] + red[1][e] + red[2][e] + red[3][e] + gb[e];
            mx = fmaxf(mx, lg[e]);
        }
        float sum = 0.f;
        for (int e = 0; e < 5; ++e) { p[e] = expf(lg[e] - mx); sum += p[e]; }
        for (int e = 0; e < 5; ++e) p[e] /= sum;
        bool used[5] = {false, false, false, false, false};
        float out5[5] = {0, 0, 0, 0, 0};
        int ti[3]; float tv[3]; float tsum = 0.f;
        for (int jj = 0; jj < 3; ++jj) {
            int best = 0; float bv = -1.f;
            for (int e = 0; e < 5; ++e)
                if (!used[e] && p[e] > bv) { bv = p[e]; best = e; }
            used[best] = true; ti[jj] = best; tv[jj] = bv; tsum += bv;
        }
        for (int jj = 0; jj < 3; ++jj) out5[ti[jj]] = tv[jj] / tsum;
        for (int e = 0; e < 5; ++e) wfull[b * 5 + e] = out5[e];
    }
}

// ---------------- kernel 1b: token compaction — per-expert row lists (top-3 sparsity)
__global__ __launch_bounds__(256) void k_compact(
    const float* __restrict__ wfull, int* __restrict__ cnt, int* __restrict__ lists)
{
    int tok = blockIdx.x * 256 + threadIdx.x;
    int lane = threadIdx.x & 63;
    float w[5];
    #pragma unroll
    for (int e = 0; e < 5; ++e) w[e] = wfull[(size_t)tok * 5 + e];
    #pragma unroll
    for (int e = 0; e < 5; ++e) {
        bool sel = w[e] > 0.f;
        unsigned long long mask = __ballot(sel);
        int leader = __ffsll((long long)mask) - 1;
        int base = 0;
        if (lane == leader) base = atomicAdd(&cnt[e], __popcll(mask));
        base = __shfl(base, leader, 64);
        if (sel) {
            int pos = base + __popcll(mask & ((1ull << lane) - 1ull));
            lists[e * NB + pos] = tok;
        }
    }
}

// ---------------- kernel 2: fused experts on COMPACTED token lists.
// grid 640 fixed (graph-safe); e = bid/128 (one B matrix hot per L2 at a time);
// blocks past ceil(cnt_e/64) exit. A rows gathered via per-lane global_load_lds addrs.
#define H1S 136
union SLds {
    struct { _Float16 As[64 * 32]; _Float16 Bs[128 * 32]; } p1;  // e1 staging (unpadded)
    _Float16 e2ws[128 * H1S];                                    // e2 weights (padded)
};

__global__ __launch_bounds__(256, 3) void k_e1e2(
    const _Float16* __restrict__ h16, const _Float16* __restrict__ wT,
    const _Float16* __restrict__ e2T,
    const float* __restrict__ e1b, const float* __restrict__ e2b,
    const float* __restrict__ wfull, const int* __restrict__ cnt,
    const int* __restrict__ lists, float* __restrict__ moe)
{
    __shared__ SLds u;
    __shared__ __align__(16) _Float16 h1s[64 * H1S];
    __shared__ float wfl[64];
    __shared__ int rows[64];
    int bid = blockIdx.x;
    int e = bid >> 7;            // 0..4
    int mt = bid & 127;
    int cnt_e = cnt[e];
    int m0 = mt * 64;
    if (m0 >= cnt_e) return;     // inactive tile, uniform exit
    int t = threadIdx.x;
    int lane = t & 63, wv = t >> 6;
    int waveM = wv >> 1, waveN = wv & 1;
    int quad = lane >> 4, l16 = lane & 15;
    if (t < 64) {
        int r = m0 + t;
        int row = (r < cnt_e) ? lists[e * NB + r] : lists[e * NB];  // dup row for tail
        rows[t] = row;
        wfl[t] = (r < cnt_e) ? wfull[(size_t)row * 5 + e] : 0.f;
    }
    __syncthreads();

    const _Float16* bbase = wT + (size_t)e * (D_H * D_IN);
    int srow = t >> 2;               // 0..63
    int scol = (t & 3) * 8;
    const _Float16* aptr = h16 + (size_t)rows[srow] * D_IN + scol;  // gathered row
    f32x4 acc[2][4];
    #pragma unroll
    for (int i = 0; i < 2; ++i)
        #pragma unroll
        for (int j = 0; j < 4; ++j) acc[i][j] = (f32x4){0.f, 0.f, 0.f, 0.f};

    for (int k0 = 0; k0 < D_IN; k0 += 32) {
        gload16(aptr + k0,                                      u.p1.As + wv * 512);
        gload16(bbase + (size_t)srow * D_IN + k0 + scol,        u.p1.Bs + wv * 512);
        gload16(bbase + (size_t)(64 + srow) * D_IN + k0 + scol, u.p1.Bs + 2048 + wv * 512);
        __syncthreads();
        f16x8 af[2], bf[4];
        #pragma unroll
        for (int ms = 0; ms < 2; ++ms)
            af[ms] = *(const f16x8*)&u.p1.As[(waveM * 32 + ms * 16 + l16) * 32 + quad * 8];
        #pragma unroll
        for (int ns = 0; ns < 4; ++ns)
            bf[ns] = *(const f16x8*)&u.p1.Bs[(waveN * 64 + ns * 16 + l16) * 32 + quad * 8];
        #pragma unroll
        for (int ms = 0; ms < 2; ++ms)
            #pragma unroll
            for (int ns = 0; ns < 4; ++ns)
                acc[ms][ns] = __builtin_amdgcn_mfma_f32_16x16x32_f16(af[ms], bf[ns], acc[ms][ns], 0, 0, 0);
        __syncthreads();
    }

    #pragma unroll
    for (int ms = 0; ms < 2; ++ms) {
        int rbase = waveM * 32 + ms * 16 + quad * 4;
        #pragma unroll
        for (int ns = 0; ns < 4; ++ns) {
            int n = waveN * 64 + ns * 16 + l16;
            float bias = e1b[e * D_H + n];
            #pragma unroll
            for (int r = 0; r < 4; ++r)
                h1s[(rbase + r) * H1S + n] = (_Float16)tanhf(acc[ms][ns][r] + bias);
        }
    }
    __syncthreads();

    {
        int rr = t >> 1, cc = (t & 1) * 64;
        const _Float16* src = e2T + (size_t)e * (D_H * D_H) + (size_t)rr * D_H + cc;
        #pragma unroll
        for (int i = 0; i < 8; ++i)
            *(uint4*)&u.e2ws[rr * H1S + cc + i * 8] = *(const uint4*)(src + i * 8);
    }
    __syncthreads();

    f32x4 acc2[2][4];
    #pragma unroll
    for (int i = 0; i < 2; ++i)
        #pragma unroll
        for (int j = 0; j < 4; ++j) acc2[i][j] = (f32x4){0.f, 0.f, 0.f, 0.f};
    #pragma unroll
    for (int kc = 0; kc < 4; ++kc) {
        f16x8 a2[2], b2[4];
        #pragma unroll
        for (int ms = 0; ms < 2; ++ms)
            a2[ms] = *(const f16x8*)&h1s[(waveM * 32 + ms * 16 + l16) * H1S + kc * 32 + quad * 8];
        #pragma unroll
        for (int ns = 0; ns < 4; ++ns)
            b2[ns] = *(const f16x8*)&u.e2ws[(waveN * 64 + ns * 16 + l16) * H1S + kc * 32 + quad * 8];
        #pragma unroll
        for (int ms = 0; ms < 2; ++ms)
            #pragma unroll
            for (int ns = 0; ns < 4; ++ns)
                acc2[ms][ns] = __builtin_amdgcn_mfma_f32_16x16x32_f16(a2[ms], b2[ns], acc2[ms][ns], 0, 0, 0);
    }

    #pragma unroll
    for (int ms = 0; ms < 2; ++ms) {
        int rbase = waveM * 32 + ms * 16 + quad * 4;
        #pragma unroll
        for (int ns = 0; ns < 4; ++ns) {
            int n = waveN * 64 + ns * 16 + l16;
            float bias = e2b[e * D_H + n];
            #pragma unroll
            for (int r = 0; r < 4; ++r) {
                int lrow = rbase + r;
                float w = wfl[lrow];
                if (w != 0.f) {
                    float h2 = tanhf(acc2[ms][ns][r] + bias);
                    unsafeAtomicAdd(&moe[(size_t)rows[lrow] * D_H + n], w * h2);
                }
            }
        }
    }
}

// ---------------- kernel 3: head: logits = moe @ smw + smb, softmax -> out
__global__ __launch_bounds__(256) void k_head(
    const float* __restrict__ moe, const float* __restrict__ smw,
    const float* __restrict__ smb, float* __restrict__ out)
{
    __shared__ float moesT[128 * 66];
    __shared__ float smws[1280];
    __shared__ float smbs[16];
    __shared__ float lg[64 * 12];
    int b0 = blockIdx.x * 64;
    int t = threadIdx.x;
    for (int i = t; i < 1280; i += 256) smws[i] = smw[i];
    if (t < 10) smbs[t] = smb[t];
    {
        int row = t >> 2, cb = (t & 3) * 32;
        #pragma unroll
        for (int i = 0; i < 8; ++i) {
            float4 v = *(const float4*)&moe[(size_t)(b0 + row) * D_H + cb + i * 4];
            moesT[(cb + i * 4 + 0) * 66 + row] = v.x;
            moesT[(cb + i * 4 + 1) * 66 + row] = v.y;
            moesT[(cb + i * 4 + 2) * 66 + row] = v.z;
            moesT[(cb + i * 4 + 3) * 66 + row] = v.w;
        }
    }
    __syncthreads();
    {
        int row = t & 63, grp = t >> 6;
        int c0 = grp, c1 = grp + 4, c2 = grp + 8;
        float s0 = 0.f, s1 = 0.f, s2 = 0.f;
        for (int k = 0; k < 128; ++k) {
            float m = moesT[k * 66 + row];
            s0 += m * smws[k * 10 + c0];
            s1 += m * smws[k * 10 + c1];
            if (c2 < 10) s2 += m * smws[k * 10 + c2];
        }
        lg[row * 12 + c0] = s0 + smbs[c0];
        lg[row * 12 + c1] = s1 + smbs[c1];
        if (c2 < 10) lg[row * 12 + c2] = s2 + smbs[c2];
    }
    __syncthreads();
    if (t < 64) {
        float mx = -1e30f;
        for (int c = 0; c < 10; ++c) mx = fmaxf(mx, lg[t * 12 + c]);
        float s = 0.f, ex[10];
        for (int c = 0; c < 10; ++c) { ex[c] = expf(lg[t * 12 + c] - mx); s += ex[c]; }
        float inv = 1.f / s;
        for (int c = 0; c < 10; ++c) out[(size_t)(b0 + t) * 10 + c] = ex[c] * inv;
    }
}

extern "C" void kernel_launch(void* const* d_in, const int* in_sizes, int n_in,
                              void* d_out, int out_size, void* d_ws, size_t ws_size,
                              hipStream_t stream)
{
    const float* x   = (const float*)d_in[0];
    const float* c1w = (const float*)d_in[1];
    const float* c1b = (const float*)d_in[2];
    const float* c2w = (const float*)d_in[3];
    const float* c2b = (const float*)d_in[4];
    const float* gw  = (const float*)d_in[5];
    const float* gb  = (const float*)d_in[6];
    const float* e1w = (const float*)d_in[7];
    const float* e1b = (const float*)d_in[8];
    const float* e2w = (const float*)d_in[9];
    const float* e2b = (const float*)d_in[10];
    const float* smw = (const float*)d_in[11];
    const float* smb = (const float*)d_in[12];
    float* out = (float*)d_out;

    char* ws = (char*)d_ws;
    size_t off = 0;
    auto alloc = [&](size_t bytes) {
        void* p = ws + off;
        off += (bytes + 255) & ~(size_t)255;
        return p;
    };
    _Float16* h16 = (_Float16*)alloc((size_t)NB * D_IN * 2);          // 52.4 MB
    _Float16* wT  = (_Float16*)alloc((size_t)NE * D_H * D_IN * 2);    // 4.1 MB
    _Float16* e2T = (_Float16*)alloc((size_t)NE * D_H * D_H * 2);     // 0.16 MB
    float* wfull  = (float*)alloc((size_t)NB * NE * 4);               // 0.16 MB
    float* moe    = (float*)alloc((size_t)NB * D_H * 4);              // 4.2 MB
    float* gwC    = (float*)alloc((size_t)NE * D_IN * 4);             // 64 KB
    int* cnt      = (int*)alloc(NE * 4);
    int* lists    = (int*)alloc((size_t)NE * NB * 4);                 // 160 KB

    hipMemsetAsync(moe, 0, (size_t)NB * D_H * 4, stream);
    hipMemsetAsync(cnt, 0, NE * 4, stream);
    k_wconv<<<dim3(NE, D_IN / 64, D_H / 64), 256, 0, stream>>>(e1w, wT);
    k_wprep2<<<dim3(NE, 2, 2), 256, 0, stream>>>(e2w, e2T);
    k_wgate<<<dim3(63), 256, 0, stream>>>(gw, gwC);
    k_feat<<<dim3(NB), 256, 0, stream>>>(x, c1w, c1b, c2w, c2b, gwC, gb, h16, wfull);
    k_compact<<<dim3(NB / 256), 256, 0, stream>>>(wfull, cnt, lists);
    k_e1e2<<<dim3(128 * NE), 256, 0, stream>>>(h16, wT, e2T, e1b, e2b, wfull, cnt, lists, moe);
    k_head<<<dim3(NB / 64), 256, 0, stream>>>(moe, smw, smb, out);
}